// Round 47
// baseline (20.549 us; speedup 1.0000x reference)
//
#include <hip/hip_runtime.h>
#include <math.h>

// Problem constants (fixed by setup_inputs)
#define NOBJ 256
#define HDIM 512
#define WDIM 512
#define EPSF 1e-6f

// d_out layout (floats): [0, 262144) = M_hat ; [262144] = loss ; [262145, 262657) = centers (N,2)
#define OUT_LOSS (HDIM * WDIM)
#define OUT_CTR  (HDIM * WDIM + 1)

// d_ws layout (floats): [0,256) = per-block heat partials ; [256] = L_box
#define WS_PART 0
#define WS_LBOX 256

// ---------------------------------------------------------------------------
// Kernel 1: centers, s_hat/o_hat, L_box (deterministic block reduction)
// ---------------------------------------------------------------------------
__global__ __launch_bounds__(256) void prep_kernel(
    const float* __restrict__ boxes, const float* __restrict__ s,
    const float* __restrict__ o, float* __restrict__ out,
    float* __restrict__ ws) {
  int n = threadIdx.x;  // 256 threads == NOBJ
  float b0 = boxes[n * 4 + 0];
  float b1 = boxes[n * 4 + 1];
  float b2 = boxes[n * 4 + 2];
  float b3 = boxes[n * 4 + 3];
  float cx = (b0 + b2) * 0.5f;
  float cy = (b1 + b3) * 0.5f;
  out[OUT_CTR + 2 * n + 0] = cx;
  out[OUT_CTR + 2 * n + 1] = cy;

  float sh0 = b2 - b0, sh1 = b3 - b1;
  float qx = cx * 0.25f, qy = cy * 0.25f;           // centers / STRIDE(4)
  float oh0 = qx - floorf(qx), oh1 = qy - floorf(qy);
  float lb = fabsf(o[2 * n + 0] - oh0) + fabsf(o[2 * n + 1] - oh1) +
             0.1f * (fabsf(s[2 * n + 0] - sh0) + fabsf(s[2 * n + 1] - sh1));

  // deterministic reduction: wave shuffle tree + 4-wave LDS combine
  for (int off = 32; off; off >>= 1) lb += __shfl_down(lb, off, 64);
  __shared__ float red[4];
  if ((threadIdx.x & 63) == 0) red[threadIdx.x >> 6] = lb;
  __syncthreads();
  if (threadIdx.x == 0) ws[WS_LBOX] = (red[0] + red[1]) + (red[2] + red[3]);
}

// ---------------------------------------------------------------------------
// Kernel 2: per 32x32 tile — build Ex/Ey slices in LDS (expf), rank-256
// accumulate (2x2 register blocking), fused M_hat store + heat-loss partial.
// ---------------------------------------------------------------------------
__device__ __forceinline__ float heat_term(float mhat, float Mv) {
  float mh = fminf(fmaxf(mhat, EPSF), 1.0f - EPSF);
  float pos = (1.0f - mh) * logf(mh);
  float neg = (1.0f - Mv) * mh * logf(1.0f - mh);
  return (Mv == 1.0f) ? pos : neg;
}

__global__ __launch_bounds__(256) void heat_kernel(
    const float* __restrict__ M, const int* __restrict__ stdev_p,
    float* __restrict__ out, float* __restrict__ ws) {
  // 64 KiB LDS: exS = lds[0:8192) as [k=256][r=32], eyS = lds[8192:16384)
  __shared__ float lds[16384];
  float* exS = lds;
  float* eyS = lds + 8192;

  const float* ctr = out + OUT_CTR;  // written by prep_kernel (same stream)
  const int tx = threadIdx.x, ty = threadIdx.y;
  const int tid = ty * 16 + tx;
  const int h0 = blockIdx.y * 32, w0 = blockIdx.x * 32;

  float sd = (float)stdev_p[0];
  float inv = 1.0f / (2.0f * sd * sd);

  // --- table phase: 64 exps/thread; lanes write consecutive r -> no conflicts
  {
    const int r = tid & 31;        // local row/col 0..31
    const int kb = tid >> 5;       // 0..7
    const float fr_h = (float)(h0 + r);
    const float fr_w = (float)(w0 + r);
#pragma unroll 4
    for (int j = 0; j < 32; ++j) {
      int k = kb + 8 * j;          // uniform across 32-lane groups
      float cx = ctr[2 * k + 0];
      float cy = ctr[2 * k + 1];
      float dx = fr_h - cx;
      float dy = fr_w - cy;
      exS[k * 32 + r] = expf(-dx * dx * inv);
      eyS[k * 32 + r] = expf(-dy * dy * inv);
    }
  }
  __syncthreads();

  // --- rank-256 accumulation, 2x2 per thread, float2 LDS reads (k-major,
  // bank-conflict-free: ex banks {2ty,2ty+1}, ey banks {2tx,2tx+1})
  float a00 = 0.f, a01 = 0.f, a10 = 0.f, a11 = 0.f;
#pragma unroll 8
  for (int k = 0; k < NOBJ; ++k) {
    float2 ea = *(const float2*)&exS[k * 32 + 2 * ty];
    float2 ec = *(const float2*)&eyS[k * 32 + 2 * tx];
    a00 += ea.x * ec.x;
    a01 += ea.x * ec.y;
    a10 += ea.y * ec.x;
    a11 += ea.y * ec.y;
  }

  // --- fused store + loss
  const int r0 = h0 + 2 * ty, r1 = r0 + 1;
  const int c0 = w0 + 2 * tx;
  float2 m0 = *(const float2*)&M[r0 * WDIM + c0];
  float2 m1 = *(const float2*)&M[r1 * WDIM + c0];
  *(float2*)&out[r0 * WDIM + c0] = make_float2(a00, a01);
  *(float2*)&out[r1 * WDIM + c0] = make_float2(a10, a11);

  float t = heat_term(a00, m0.x) + heat_term(a01, m0.y) +
            heat_term(a10, m1.x) + heat_term(a11, m1.y);

  // deterministic block reduction (reuse lds after barrier)
  for (int off = 32; off; off >>= 1) t += __shfl_down(t, off, 64);
  __syncthreads();  // all k-loop LDS reads complete before reuse
  if ((tid & 63) == 0) lds[tid >> 6] = t;
  __syncthreads();
  if (tid == 0)
    ws[WS_PART + blockIdx.y * 16 + blockIdx.x] =
        (lds[0] + lds[1]) + (lds[2] + lds[3]);
}

// ---------------------------------------------------------------------------
// Kernel 3: fixed-order reduce of 256 partials + L_box -> loss scalar
// ---------------------------------------------------------------------------
__global__ __launch_bounds__(256) void final_kernel(const float* __restrict__ ws,
                                                    float* __restrict__ out) {
  float v = ws[WS_PART + threadIdx.x];
  for (int off = 32; off; off >>= 1) v += __shfl_down(v, off, 64);
  __shared__ float red[4];
  if ((threadIdx.x & 63) == 0) red[threadIdx.x >> 6] = v;
  __syncthreads();
  if (threadIdx.x == 0)
    out[OUT_LOSS] = (red[0] + red[1]) + (red[2] + red[3]) + ws[WS_LBOX];
}

// ---------------------------------------------------------------------------
extern "C" void kernel_launch(void* const* d_in, const int* in_sizes, int n_in,
                              void* d_out, int out_size, void* d_ws,
                              size_t ws_size, hipStream_t stream) {
  const float* boxes = (const float*)d_in[0];
  const float* M     = (const float*)d_in[1];
  const float* s     = (const float*)d_in[2];
  const float* o     = (const float*)d_in[3];
  const int*   stdev = (const int*)d_in[4];
  float* out = (float*)d_out;
  float* ws  = (float*)d_ws;

  prep_kernel<<<1, 256, 0, stream>>>(boxes, s, o, out, ws);
  heat_kernel<<<dim3(16, 16), dim3(16, 16), 0, stream>>>(M, stdev, out, ws);
  final_kernel<<<1, 256, 0, stream>>>(ws, out);
}

// Round 48
// 15.592 us; speedup vs baseline: 1.3179x; 1.3179x over previous
//
#include <hip/hip_runtime.h>
#include <math.h>

// Problem constants (fixed by setup_inputs)
#define NOBJ 256
#define HDIM 512
#define WDIM 512
#define EPSF 1e-6f

// d_out layout (floats): [0, 262144) = M_hat ; [262144] = loss ; [262145, 262657) = centers (N,2)
#define OUT_LOSS (HDIM * WDIM)
#define OUT_CTR  (HDIM * WDIM + 1)

// d_ws layout (floats): [0,256) = per-block heat partials ; [256] = L_box
#define WS_PART 0
#define WS_LBOX 256

// ---------------------------------------------------------------------------
// Kernel 1 (fused): per 32x32 tile — centers computed on-the-fly from boxes
// (4 KB, L1-resident); block (0,0) additionally writes centers + L_box.
// Ex/Ey LDS tables via expf, rank-256 accumulation (2x2 register blocking),
// fused M_hat store + heat-loss partial.
// ---------------------------------------------------------------------------
__device__ __forceinline__ float heat_term(float mhat, float Mv) {
  float mh = fminf(fmaxf(mhat, EPSF), 1.0f - EPSF);
  float pos = (1.0f - mh) * logf(mh);
  float neg = (1.0f - Mv) * mh * logf(1.0f - mh);
  return (Mv == 1.0f) ? pos : neg;
}

__global__ __launch_bounds__(256) void heat_fused_kernel(
    const float* __restrict__ boxes, const float* __restrict__ M,
    const float* __restrict__ s, const float* __restrict__ o,
    const int* __restrict__ stdev_p, float* __restrict__ out,
    float* __restrict__ ws) {
  // 64 KiB LDS: exS = lds[0:8192) as [k=256][r=32], eyS = lds[8192:16384)
  __shared__ float lds[16384];
  float* exS = lds;
  float* eyS = lds + 8192;

  const float4* boxes4 = (const float4*)boxes;
  const int tx = threadIdx.x, ty = threadIdx.y;
  const int tid = ty * 16 + tx;
  const int h0 = blockIdx.y * 32, w0 = blockIdx.x * 32;

  // --- prep section (block 0 only): centers out + L_box (reuses lds, then bar)
  if (blockIdx.x == 0 && blockIdx.y == 0) {
    float4 b = boxes4[tid];                       // tid == object index
    float cx = (b.x + b.z) * 0.5f;
    float cy = (b.y + b.w) * 0.5f;
    out[OUT_CTR + 2 * tid + 0] = cx;
    out[OUT_CTR + 2 * tid + 1] = cy;

    float sh0 = b.z - b.x, sh1 = b.w - b.y;
    float qx = cx * 0.25f, qy = cy * 0.25f;       // centers / STRIDE(4)
    float oh0 = qx - floorf(qx), oh1 = qy - floorf(qy);
    float lb = fabsf(o[2 * tid + 0] - oh0) + fabsf(o[2 * tid + 1] - oh1) +
               0.1f * (fabsf(s[2 * tid + 0] - sh0) + fabsf(s[2 * tid + 1] - sh1));
    for (int off = 32; off; off >>= 1) lb += __shfl_down(lb, off, 64);
    if ((tid & 63) == 0) lds[tid >> 6] = lb;
    __syncthreads();
    if (tid == 0) ws[WS_LBOX] = (lds[0] + lds[1]) + (lds[2] + lds[3]);
    __syncthreads();  // lds free for table phase
  }

  float sd = (float)stdev_p[0];
  float inv = 1.0f / (2.0f * sd * sd);

  // --- table phase: centers on the fly (boxes is 4 KB -> L1); 64 exps/thread
  {
    const int r = tid & 31;        // local row/col 0..31
    const int kb = tid >> 5;       // 0..7
    const float fr_h = (float)(h0 + r);
    const float fr_w = (float)(w0 + r);
#pragma unroll 4
    for (int j = 0; j < 32; ++j) {
      int k = kb + 8 * j;          // uniform across 32-lane groups
      float4 b = boxes4[k];
      float cx = (b.x + b.z) * 0.5f;
      float cy = (b.y + b.w) * 0.5f;
      float dx = fr_h - cx;
      float dy = fr_w - cy;
      exS[k * 32 + r] = expf(-dx * dx * inv);
      eyS[k * 32 + r] = expf(-dy * dy * inv);
    }
  }
  __syncthreads();

  // --- rank-256 accumulation, 2x2 per thread, float2 LDS reads (k-major,
  // bank-conflict-free: ex banks {2ty,2ty+1}, ey banks {2tx,2tx+1})
  float a00 = 0.f, a01 = 0.f, a10 = 0.f, a11 = 0.f;
#pragma unroll 8
  for (int k = 0; k < NOBJ; ++k) {
    float2 ea = *(const float2*)&exS[k * 32 + 2 * ty];
    float2 ec = *(const float2*)&eyS[k * 32 + 2 * tx];
    a00 += ea.x * ec.x;
    a01 += ea.x * ec.y;
    a10 += ea.y * ec.x;
    a11 += ea.y * ec.y;
  }

  // --- fused store + loss
  const int r0 = h0 + 2 * ty, r1 = r0 + 1;
  const int c0 = w0 + 2 * tx;
  float2 m0 = *(const float2*)&M[r0 * WDIM + c0];
  float2 m1 = *(const float2*)&M[r1 * WDIM + c0];
  *(float2*)&out[r0 * WDIM + c0] = make_float2(a00, a01);
  *(float2*)&out[r1 * WDIM + c0] = make_float2(a10, a11);

  float t = heat_term(a00, m0.x) + heat_term(a01, m0.y) +
            heat_term(a10, m1.x) + heat_term(a11, m1.y);

  // deterministic block reduction (reuse lds after barrier)
  for (int off = 32; off; off >>= 1) t += __shfl_down(t, off, 64);
  __syncthreads();  // all k-loop LDS reads complete before reuse
  if ((tid & 63) == 0) lds[tid >> 6] = t;
  __syncthreads();
  if (tid == 0)
    ws[WS_PART + blockIdx.y * 16 + blockIdx.x] =
        (lds[0] + lds[1]) + (lds[2] + lds[3]);
}

// ---------------------------------------------------------------------------
// Kernel 2: fixed-order reduce of 256 partials + L_box -> loss scalar
// ---------------------------------------------------------------------------
__global__ __launch_bounds__(256) void final_kernel(const float* __restrict__ ws,
                                                    float* __restrict__ out) {
  float v = ws[WS_PART + threadIdx.x];
  for (int off = 32; off; off >>= 1) v += __shfl_down(v, off, 64);
  __shared__ float red[4];
  if ((threadIdx.x & 63) == 0) red[threadIdx.x >> 6] = v;
  __syncthreads();
  if (threadIdx.x == 0)
    out[OUT_LOSS] = (red[0] + red[1]) + (red[2] + red[3]) + ws[WS_LBOX];
}

// ---------------------------------------------------------------------------
extern "C" void kernel_launch(void* const* d_in, const int* in_sizes, int n_in,
                              void* d_out, int out_size, void* d_ws,
                              size_t ws_size, hipStream_t stream) {
  const float* boxes = (const float*)d_in[0];
  const float* M     = (const float*)d_in[1];
  const float* s     = (const float*)d_in[2];
  const float* o     = (const float*)d_in[3];
  const int*   stdev = (const int*)d_in[4];
  float* out = (float*)d_out;
  float* ws  = (float*)d_ws;

  heat_fused_kernel<<<dim3(16, 16), dim3(16, 16), 0, stream>>>(
      boxes, M, s, o, stdev, out, ws);
  final_kernel<<<1, 256, 0, stream>>>(ws, out);
}